// Round 7
// baseline (271.721 us; speedup 1.0000x reference)
//
#include <hip/hip_runtime.h>
#include <stdint.h>

typedef __attribute__((ext_vector_type(8))) short bf16x8;
typedef __attribute__((ext_vector_type(4))) float f32x4;

#define HH  100   // history length
#define DD  128   // embedding dim d
#define HID 256   // hidden width / concat dim
#define NT  7     // m-tiles (112 rows >= 100)

__device__ __forceinline__ unsigned short f2bf(float f) {
    unsigned int u = __float_as_uint(f);
    u += 0x7fffu + ((u >> 16) & 1u);   // RNE
    return (unsigned short)(u >> 16);
}

// Pack W1 (256x256 f32, [n][k]) into MFMA fragment order, bf16 (runs once).
// unit = (st*8+s)*64 + lane holds W1[st*16 + (lane&15)][s*32 + (lane>>4)*8 + j]
__global__ void w1_pack(const float* __restrict__ W1, unsigned short* __restrict__ W1p) {
    int unit = blockIdx.x * 256 + threadIdx.x;   // 0..8191
    int lane = unit & 63;
    int s    = (unit >> 6) & 7;
    int st   = unit >> 9;
    int col  = lane & 15, quad = lane >> 4;
    const float* src = W1 + (size_t)(st * 16 + col) * HID + s * 32 + quad * 8;
    union { unsigned short u[8]; bf16x8 v; } o;
    #pragma unroll
    for (int j = 0; j < 8; j++) o.u[j] = f2bf(src[j]);
    *(bf16x8*)(W1p + (size_t)unit * 8) = o.v;
}

// pure-VALU packed bf16 convert (no memory side effects — safe asm)
__device__ __forceinline__ unsigned int cvt_pk_bf16(float lo, float hi) {
    unsigned int r;   // r[15:0]=bf16(lo), r[31:16]=bf16(hi)
    asm("v_cvt_pk_bf16_f32 %0, %1, %2" : "=v"(r) : "v"(lo), "v"(hi));
    return r;
}

// multiply 2 float4 by tgt slice, accumulate xsum, cvt+store one A-frag s-step
#define CONSUME(V0, V1, S, AP, TGT, ACC) do {                                     \
    const float* tp_ = (TGT) + (S) * 32 + quad * 8;                               \
    float4 t0_ = *(const float4*)tp_, t1_ = *(const float4*)(tp_ + 4);            \
    float x0=(V0).x*t0_.x, x1=(V0).y*t0_.y, x2=(V0).z*t0_.z, x3=(V0).w*t0_.w;     \
    float x4=(V1).x*t1_.x, x5=(V1).y*t1_.y, x6=(V1).z*t1_.z, x7=(V1).w*t1_.w;     \
    (ACC) += (x0+x1)+(x2+x3)+((x4+x5)+(x6+x7));                                   \
    union { unsigned int u[4]; int4 v; } fb_;                                     \
    fb_.u[0]=cvt_pk_bf16(x0,x1); fb_.u[1]=cvt_pk_bf16(x2,x3);                     \
    fb_.u[2]=cvt_pk_bf16(x4,x5); fb_.u[3]=cvt_pk_bf16(x6,x7);                     \
    *(int4*)((AP) + (size_t)((S) * 64 + lane) * 8) = fb_.v;                       \
} while (0)

#define MFMA_PAIR(MM0, MM1) do {                                                  \
    int m0_ = (MM0); if (m0_ >= NT) m0_ -= NT;                                    \
    int m1_ = (MM1); if (m1_ >= NT) m1_ -= NT;                                    \
    const unsigned short* a0p_ = Ab + m0_ * 4096;                                 \
    const unsigned short* a1p_ = Ab + m1_ * 4096;                                 \
    f32x4 c00_={0,0,0,0}, c01_={0,0,0,0}, c10_={0,0,0,0}, c11_={0,0,0,0};         \
    _Pragma("unroll")                                                             \
    for (int s_ = 0; s_ < 8; s_++) {                                              \
        bf16x8 x0_ = *(const bf16x8*)(a0p_ + (size_t)(s_ * 64 + lane) * 8);       \
        bf16x8 x1_ = *(const bf16x8*)(a1p_ + (size_t)(s_ * 64 + lane) * 8);       \
        c00_ = __builtin_amdgcn_mfma_f32_16x16x32_bf16(w1f[s_],     x0_, c00_, 0,0,0); \
        c01_ = __builtin_amdgcn_mfma_f32_16x16x32_bf16(w1f[8 + s_], x0_, c01_, 0,0,0); \
        c10_ = __builtin_amdgcn_mfma_f32_16x16x32_bf16(w1f[s_],     x1_, c10_, 0,0,0); \
        c11_ = __builtin_amdgcn_mfma_f32_16x16x32_bf16(w1f[8 + s_], x1_, c11_, 0,0,0); \
    }                                                                             \
    float sp0_ = 0.f, sp1_ = 0.f;                                                 \
    _Pragma("unroll")                                                             \
    for (int r_ = 0; r_ < 4; r_++) {                                              \
        float z00_=c00_[r_]+bb0[r_], z01_=c01_[r_]+bb1[r_];                       \
        float z10_=c10_[r_]+bb0[r_], z11_=c11_[r_]+bb1[r_];                       \
        sp0_ += ((z00_>0.f)?z00_*ww0[r_]:0.f) + ((z01_>0.f)?z01_*ww1[r_]:0.f);    \
        sp1_ += ((z10_>0.f)?z10_*ww0[r_]:0.f) + ((z11_>0.f)?z11_*ww1[r_]:0.f);    \
    }                                                                             \
    sp0_ += __shfl_xor(sp0_, 16); sp0_ += __shfl_xor(sp0_, 32);                   \
    sp1_ += __shfl_xor(sp1_, 16); sp1_ += __shfl_xor(sp1_, 32);                   \
    if (quad == 0) {                                                              \
        scorep[wave][m0_ * 16 + col] = sp0_;                                      \
        scorep[wave][m1_ * 16 + col] = sp1_;                                      \
    }                                                                             \
} while (0)

#define MFMA_SINGLE(MM0) do {                                                     \
    int m0_ = (MM0); if (m0_ >= NT) m0_ -= NT;                                    \
    const unsigned short* a0p_ = Ab + m0_ * 4096;                                 \
    f32x4 c00_={0,0,0,0}, c01_={0,0,0,0};                                         \
    _Pragma("unroll")                                                             \
    for (int s_ = 0; s_ < 8; s_++) {                                              \
        bf16x8 x0_ = *(const bf16x8*)(a0p_ + (size_t)(s_ * 64 + lane) * 8);       \
        c00_ = __builtin_amdgcn_mfma_f32_16x16x32_bf16(w1f[s_],     x0_, c00_, 0,0,0); \
        c01_ = __builtin_amdgcn_mfma_f32_16x16x32_bf16(w1f[8 + s_], x0_, c01_, 0,0,0); \
    }                                                                             \
    float sp0_ = 0.f;                                                             \
    _Pragma("unroll")                                                             \
    for (int r_ = 0; r_ < 4; r_++) {                                              \
        float z00_=c00_[r_]+bb0[r_], z01_=c01_[r_]+bb1[r_];                       \
        sp0_ += ((z00_>0.f)?z00_*ww0[r_]:0.f) + ((z01_>0.f)?z01_*ww1[r_]:0.f);    \
    }                                                                             \
    sp0_ += __shfl_xor(sp0_, 16); sp0_ += __shfl_xor(sp0_, 32);                   \
    if (quad == 0) scorep[wave][m0_ * 16 + col] = sp0_;                           \
} while (0)

// Pipelined persistent blocks at 2 BLOCKS/CU (the round-2 TLP + round-5 pipeline):
// As is SINGLE-buffered (sweep of e_i and consume of e_{i+1} are in different
// barrier-separated regions, so the double buffer was never needed) -> LDS ~70 KB
// -> 2 blocks resident. launch_bounds(512,4) caps regs at 128 (round-5 body = 120).
// Gather split: hist-half loads issued in the sweep region; reg-half issued at the
// top of region 2 so softmax+consume-hist VALU hides their latency.
__global__ __launch_bounds__(512, 4) void nais_kernel(
    const int* __restrict__ history,           // [B,HH]
    const int* __restrict__ target,            // [B]
    const int* __restrict__ history_region,    // [B,HH]
    const int* __restrict__ target_region,     // [B]
    const float* __restrict__ target_distance, // [B]
    const float* __restrict__ E_hist,          // [item,128]
    const float* __restrict__ E_tgt,           // [item,128]
    const float* __restrict__ E_reg,           // [region,128]
    const float* __restrict__ E_dist,          // [16,128]
    const float* __restrict__ b1,              // [256]
    const float* __restrict__ w2,              // [256]
    const unsigned short* __restrict__ W1p,    // packed bf16 fragments (128 KB)
    float* __restrict__ out,                   // [B]
    int Btot)
{
    __shared__ __align__(16) unsigned short As[NT * 4096];     // 56 KB, single buffer
    __shared__ __align__(16) float tgts3[3][HID];
    __shared__ __align__(16) float b1s[HID];
    __shared__ __align__(16) float w2s[HID];
    __shared__ __align__(16) int   hidx3[3][HH];
    __shared__ __align__(16) int   hreg3[3][HH];
    __shared__ __align__(16) float scorep[8][112];
    __shared__ __align__(16) float xsum2[2][112];
    __shared__ int   tgA[64];
    __shared__ int   trA[64];
    __shared__ float tdA[64];
    __shared__ float p12[2][4];
    __shared__ float s_sumE;

    const int t    = threadIdx.x;
    const int lane = t & 63;
    const int wave = t >> 6;
    const int col  = lane & 15;
    const int quad = lane >> 4;

    const int NB   = (Btot + gridDim.x - 1) / gridDim.x;
    const int base = blockIdx.x * NB;
    int cnt = Btot - base;
    if (cnt <= 0) return;
    if (cnt > NB) cnt = NB;

    // ---- prologue: scalars ----
    if (t < cnt) {
        tgA[t] = target[base + t];
        trA[t] = target_region[base + t];
        tdA[t] = target_distance[base + t];
    }
    if (wave == 4) {
        *(float4*)(b1s + lane * 4) = *(const float4*)(b1 + lane * 4);
        *(float4*)(w2s + lane * 4) = *(const float4*)(w2 + lane * 4);
    }
    if (wave == 5) {
        float v = E_dist[lane] + E_dist[64 + lane];
        #pragma unroll
        for (int off = 32; off; off >>= 1) v += __shfl_xor(v, off);
        if (lane == 0) s_sumE = v;
    }
    __syncthreads();   // P1

    // ---- W1 fragments -> registers, once per block, pinned ----
    bf16x8 w1f[16];
    #pragma unroll
    for (int i = 0; i < 16; i++) {
        const int unit = ((2 * wave + (i >> 3)) * 8 + (i & 7)) * 64 + lane;
        w1f[i] = *(const bf16x8*)(W1p + (size_t)unit * 8);
    }
    #pragma unroll
    for (int i = 0; i < 16; i++) asm volatile("" : "+v"(w1f[i]));

    // ---- prologue: meta for e0 (slot 0) and e1 (slot 1) ----
    if (wave < 2 && wave < cnt) {
        const int em = base + wave;
        int4 mh = {0,0,0,0}, mr = {0,0,0,0};
        if (lane < 25)      mh = *(const int4*)(history + (size_t)em * HH + lane * 4);
        else if (lane < 50) mr = *(const int4*)(history_region + (size_t)em * HH + (lane - 25) * 4);
        const int tg2 = tgA[wave], tr2 = trA[wave];
        const float* tp2 = (lane < 32) ? (E_tgt + (size_t)tg2 * DD + lane * 4)
                                       : (E_reg + (size_t)tr2 * DD + (lane - 32) * 4);
        float4 mt4 = *(const float4*)tp2;
        if (lane < 25)      *(int4*)&hidx3[wave][lane * 4] = mh;
        else if (lane < 50) *(int4*)&hreg3[wave][(lane - 25) * 4] = mr;
        *(float4*)&tgts3[wave][lane * 4] = mt4;
    }
    __syncthreads();   // P2

    // ---- prologue: gather e0 into As, xsum2[0] ----
    if (wave < NT) {
        const int row0 = wave * 16 + col;
        const int rc  = (row0 < HH) ? row0 : row0 - 64;
        const int ih  = hidx3[0][rc];
        const int ir  = hreg3[0][rc];
        const float* ph = E_hist + (size_t)ih * DD + quad * 8;
        const float* pr = E_reg  + (size_t)ir * DD + quad * 8;
        unsigned short* ap = &As[wave * 4096];
        float4 g[16];
        #pragma unroll
        for (int s = 0; s < 4; s++) {
            g[2*s]     = *(const float4*)(ph + s * 32);
            g[2*s + 1] = *(const float4*)(ph + s * 32 + 4);
            g[8 + 2*s] = *(const float4*)(pr + s * 32);
            g[9 + 2*s] = *(const float4*)(pr + s * 32 + 4);
        }
        float acc = 0.f;
        #pragma unroll
        for (int s = 0; s < 8; s++) CONSUME(g[2*s], g[2*s+1], s, ap, tgts3[0], acc);
        float v = acc;
        v += __shfl_xor(v, 16);
        v += __shfl_xor(v, 32);
        if (quad == 0) xsum2[0][row0] = v;
    }

    const int st0 = 2 * wave;
    const f32x4 bb0 = *(const f32x4*)&b1s[st0 * 16 + quad * 4];
    const f32x4 bb1 = *(const f32x4*)&b1s[st0 * 16 + 16 + quad * 4];
    const f32x4 ww0 = *(const f32x4*)&w2s[st0 * 16 + quad * 4];
    const f32x4 ww1 = *(const f32x4*)&w2s[st0 * 16 + 16 + quad * 4];

    __syncthreads();   // P3 (= iteration barrier for i=0)

    int cur = 0, cm = 0, nm = 1, n2 = 2;

    #pragma unroll 1
    for (int i = 0; i < cnt; i++) {
        const bool do_g = (i + 1 < cnt) && (wave < NT);
        const bool do_m = (i + 2 < cnt) && (wave == 7);

        // ---- R1: issue hist-half loads for e_{i+1}; MFMA sweep over As (e_i) ----
        float4 gh[8];
        const float* pr = nullptr;
        int row0 = 0;
        if (do_g) {
            row0 = wave * 16 + col;
            const int rc = (row0 < HH) ? row0 : row0 - 64;
            const int ih = hidx3[nm][rc];
            const int ir = hreg3[nm][rc];
            const float* ph = E_hist + (size_t)ih * DD + quad * 8;
            pr = E_reg + (size_t)ir * DD + quad * 8;
            #pragma unroll
            for (int s = 0; s < 4; s++) {
                gh[2*s]     = *(const float4*)(ph + s * 32);
                gh[2*s + 1] = *(const float4*)(ph + s * 32 + 4);
            }
        }
        int4 mh = {0,0,0,0}, mr4 = {0,0,0,0};
        float4 mt4 = {0.f, 0.f, 0.f, 0.f};
        if (do_m) {
            const int em = base + i + 2;
            if (lane < 25)      mh  = *(const int4*)(history + (size_t)em * HH + lane * 4);
            else if (lane < 50) mr4 = *(const int4*)(history_region + (size_t)em * HH + (lane - 25) * 4);
            const int tg2 = tgA[i + 2], tr2 = trA[i + 2];
            const float* tp2 = (lane < 32) ? (E_tgt + (size_t)tg2 * DD + lane * 4)
                                           : (E_reg + (size_t)tr2 * DD + (lane - 32) * 4);
            mt4 = *(const float4*)tp2;
        }

        const unsigned short* Ab = &As[0];

        MFMA_PAIR(wave,     wave + 1);
        MFMA_PAIR(wave + 2, wave + 3);
        MFMA_PAIR(wave + 4, wave + 5);
        MFMA_SINGLE(wave + 6);

        __syncthreads();   // B2 — sweep of e_i complete; As free for rewrite

        // ---- R2a: issue reg-half loads (latency hides under softmax below) ----
        float4 gr[8];
        if (do_g) {
            #pragma unroll
            for (int s = 0; s < 4; s++) {
                gr[2*s]     = *(const float4*)(pr + s * 32);
                gr[2*s + 1] = *(const float4*)(pr + s * 32 + 4);
            }
        }

        // ---- R2b: softmax partials for e=i; deferred finish of e-1 ----
        {
            float sc = 0.f;
            if (t < 112) {
                #pragma unroll
                for (int w = 0; w < 8; w++) sc += scorep[w][t];
            }
            float e1v = 0.f, e2v = 0.f;
            if (t < HH) {
                const float dist = tdA[i] * s_sumE;
                if (hidx3[cm][t] != tgA[i]) {
                    float ev = expf(sc + dist);
                    e1v = ev;
                    e2v = ev * xsum2[cur][t];
                }
            }
            if (wave < 2) {
                #pragma unroll
                for (int off = 32; off; off >>= 1) {
                    e1v += __shfl_xor(e1v, off);
                    e2v += __shfl_xor(e2v, off);
                }
                if (lane == 0) {
                    p12[cur][wave]     = e1v;
                    p12[cur][2 + wave] = e2v;
                }
            }
            if (i > 0 && t == 128) {     // wave 2 lane 0 finishes e-1
                float s1 = p12[cur ^ 1][0] + p12[cur ^ 1][1];
                float s2 = p12[cur ^ 1][2] + p12[cur ^ 1][3];
                float pred = s2 / sqrtf(s1);   // denom^BETA, BETA=0.5
                out[base + i - 1] = 1.f / (1.f + expf(-pred));
            }
        }

        // ---- R2c: consume both halves -> As (e_{i+1}), xsum; wave7 meta store ----
        if (do_g) {
            unsigned short* An = &As[wave * 4096];
            const float* tgt = &tgts3[nm][0];
            float acc = 0.f;
            CONSUME(gh[0], gh[1], 0, An, tgt, acc);
            CONSUME(gh[2], gh[3], 1, An, tgt, acc);
            CONSUME(gh[4], gh[5], 2, An, tgt, acc);
            CONSUME(gh[6], gh[7], 3, An, tgt, acc);
            CONSUME(gr[0], gr[1], 4, An, tgt, acc);
            CONSUME(gr[2], gr[3], 5, An, tgt, acc);
            CONSUME(gr[4], gr[5], 6, An, tgt, acc);
            CONSUME(gr[6], gr[7], 7, An, tgt, acc);
            float v = acc;
            v += __shfl_xor(v, 16);
            v += __shfl_xor(v, 32);
            if (quad == 0) xsum2[cur ^ 1][row0] = v;
        } else if (do_m) {
            if (lane < 25)      *(int4*)&hidx3[n2][lane * 4] = mh;
            else if (lane < 50) *(int4*)&hreg3[n2][(lane - 25) * 4] = mr4;
            *(float4*)&tgts3[n2][lane * 4] = mt4;
        }

        __syncthreads();   // B1 (for next iteration)
        cur ^= 1;
        const int tmp = cm; cm = nm; nm = n2; n2 = tmp;
    }

    // ---- final element finish (loop-end barrier already synced p12) ----
    if (t == 0) {
        const int sl = (cnt - 1) & 1;
        float s1 = p12[sl][0] + p12[sl][1];
        float s2 = p12[sl][2] + p12[sl][3];
        float pred = s2 / sqrtf(s1);
        out[base + cnt - 1] = 1.f / (1.f + expf(-pred));
    }
}

extern "C" void kernel_launch(void* const* d_in, const int* in_sizes, int n_in,
                              void* d_out, int out_size, void* d_ws, size_t ws_size,
                              hipStream_t stream) {
    const int*   history         = (const int*)d_in[0];
    const int*   target          = (const int*)d_in[1];
    const int*   history_region  = (const int*)d_in[2];
    const int*   target_region   = (const int*)d_in[3];
    const float* target_distance = (const float*)d_in[4];
    const float* E_hist          = (const float*)d_in[5];
    const float* E_tgt           = (const float*)d_in[6];
    const float* E_reg           = (const float*)d_in[7];
    const float* E_dist          = (const float*)d_in[8];
    const float* W1              = (const float*)d_in[9];
    const float* b1              = (const float*)d_in[10];
    const float* w2              = (const float*)d_in[11];

    unsigned short* W1p = (unsigned short*)d_ws;  // 131072 B
    const int B = in_sizes[1];

    int grid = (B + 3) / 4;          // 4 elements per block -> 2048/4 = 512 blocks
    if (grid > 512) grid = 512;      // 2 blocks/CU resident

    w1_pack<<<32, 256, 0, stream>>>(W1, W1p);
    nais_kernel<<<grid, 512, 0, stream>>>(history, target, history_region, target_region,
                                          target_distance, E_hist, E_tgt, E_reg, E_dist,
                                          b1, w2, W1p, (float*)d_out, B);
}

// Round 8
// 178.940 us; speedup vs baseline: 1.5185x; 1.5185x over previous
//
#include <hip/hip_runtime.h>
#include <stdint.h>

typedef __attribute__((ext_vector_type(8))) short bf16x8;
typedef __attribute__((ext_vector_type(4))) float f32x4;

#define HH  100   // history length
#define DD  128   // embedding dim d
#define HID 256   // hidden width / concat dim
#define NT  7     // m-tiles (112 rows >= 100)

__device__ __forceinline__ unsigned short f2bf(float f) {
    unsigned int u = __float_as_uint(f);
    u += 0x7fffu + ((u >> 16) & 1u);   // RNE
    return (unsigned short)(u >> 16);
}

// Pack W1 (256x256 f32, [n][k]) into MFMA fragment order, bf16 (runs once).
// unit = (st*8+s)*64 + lane holds W1[st*16 + (lane&15)][s*32 + (lane>>4)*8 + j]
__global__ void w1_pack(const float* __restrict__ W1, unsigned short* __restrict__ W1p) {
    int unit = blockIdx.x * 256 + threadIdx.x;   // 0..8191
    int lane = unit & 63;
    int s    = (unit >> 6) & 7;
    int st   = unit >> 9;
    int col  = lane & 15, quad = lane >> 4;
    const float* src = W1 + (size_t)(st * 16 + col) * HID + s * 32 + quad * 8;
    union { unsigned short u[8]; bf16x8 v; } o;
    #pragma unroll
    for (int j = 0; j < 8; j++) o.u[j] = f2bf(src[j]);
    *(bf16x8*)(W1p + (size_t)unit * 8) = o.v;
}

// pure-VALU packed bf16 convert (no memory side effects — safe asm)
__device__ __forceinline__ unsigned int cvt_pk_bf16(float lo, float hi) {
    unsigned int r;   // r[15:0]=bf16(lo), r[31:16]=bf16(hi)
    asm("v_cvt_pk_bf16_f32 %0, %1, %2" : "=v"(r) : "v"(lo), "v"(hi));
    return r;
}

// multiply 2 float4 by tgt slice, accumulate xsum, cvt+store one A-frag s-step
#define CONSUME(V0, V1, S, AP, TGT, ACC) do {                                     \
    const float* tp_ = (TGT) + (S) * 32 + quad * 8;                               \
    float4 t0_ = *(const float4*)tp_, t1_ = *(const float4*)(tp_ + 4);            \
    float x0=(V0).x*t0_.x, x1=(V0).y*t0_.y, x2=(V0).z*t0_.z, x3=(V0).w*t0_.w;     \
    float x4=(V1).x*t1_.x, x5=(V1).y*t1_.y, x6=(V1).z*t1_.z, x7=(V1).w*t1_.w;     \
    (ACC) += (x0+x1)+(x2+x3)+((x4+x5)+(x6+x7));                                   \
    union { unsigned int u[4]; int4 v; } fb_;                                     \
    fb_.u[0]=cvt_pk_bf16(x0,x1); fb_.u[1]=cvt_pk_bf16(x2,x3);                     \
    fb_.u[2]=cvt_pk_bf16(x4,x5); fb_.u[3]=cvt_pk_bf16(x6,x7);                     \
    *(int4*)((AP) + (size_t)((S) * 64 + lane) * 8) = fb_.v;                       \
} while (0)

// 4-wave blocks: each wave owns 64 n-columns (4 strips of 16) with W1 fragments in
// 128 registers — feasible because __launch_bounds__(256,2) gives a 256-reg/wave
// budget (round-7 lesson: 8-wave blocks at 2 blocks/CU cap at 128 regs and SPILL).
// LDS read amplification of the X broadcast drops 8x -> 4x (458 -> 229 KB/element).
// Structure otherwise identical to the verified round-2 shape: grid = B, one
// element per block, 2 blocks/CU resident, no persistence, no manual pipelining.
__global__ __launch_bounds__(256, 2) void nais_kernel(
    const int* __restrict__ history,           // [B,HH]
    const int* __restrict__ target,            // [B]
    const int* __restrict__ history_region,    // [B,HH]
    const int* __restrict__ target_region,     // [B]
    const float* __restrict__ target_distance, // [B]
    const float* __restrict__ E_hist,          // [item,128]
    const float* __restrict__ E_tgt,           // [item,128]
    const float* __restrict__ E_reg,           // [region,128]
    const float* __restrict__ E_dist,          // [16,128]
    const float* __restrict__ b1,              // [256]
    const float* __restrict__ w2,              // [256]
    const unsigned short* __restrict__ W1p,    // packed bf16 fragments (128 KB)
    float* __restrict__ out)                   // [B]
{
    __shared__ __align__(16) unsigned short As[NT * 4096];   // 56 KB
    __shared__ __align__(16) float tgts[HID];
    __shared__ __align__(16) float b1s[HID];
    __shared__ __align__(16) float w2s[HID];
    __shared__ __align__(16) float scorep[4][112];
    __shared__ __align__(16) float xsum[112];
    __shared__ float eA[HH];
    __shared__ float exs[HH];
    __shared__ int hidx[HH];
    __shared__ int hreg[HH];
    __shared__ float s_sumE;

    const int b    = blockIdx.x;
    const int t    = threadIdx.x;                // 0..255
    const int lane = t & 63;
    const int wave = t >> 6;                     // 0..3
    const int col  = lane & 15;
    const int quad = lane >> 4;

    const int   tg    = target[b];
    const float tdist = target_distance[b];

    // ---- phase 0: stage indices, tgt vector, b1/w2, sum(E_dist[0]) ----
    if (t < HH) {
        hidx[t] = history[b * HH + t];
        hreg[t] = history_region[b * HH + t];
    }
    if (wave == 2) {
        float4 v;
        if (lane < 32) v = *(const float4*)(E_tgt + (size_t)tg * DD + lane * 4);
        else           v = *(const float4*)(E_reg + (size_t)target_region[b] * DD + (lane - 32) * 4);
        *(float4*)(tgts + lane * 4) = v;
    }
    if (wave == 3) {
        *(float4*)(b1s + lane * 4) = *(const float4*)(b1 + lane * 4);
        *(float4*)(w2s + lane * 4) = *(const float4*)(w2 + lane * 4);
    }
    if (wave == 1) {
        float v = E_dist[lane] + E_dist[64 + lane];
        #pragma unroll
        for (int off = 32; off; off >>= 1) v += __shfl_xor(v, off);
        if (lane == 0) s_sumE = v;
    }
    __syncthreads();   // P1

    // ---- W1 fragments -> 128 registers/wave (4 strips x 8 s), pinned ----
    // issued first so the 32 L2-hot loads land while the gather computes
    bf16x8 w1f[32];
    #pragma unroll
    for (int j = 0; j < 32; j++) {
        const int unit = ((wave * 4 + (j >> 3)) * 8 + (j & 7)) * 64 + lane;
        w1f[j] = *(const bf16x8*)(W1p + (size_t)unit * 8);
    }
    #pragma unroll
    for (int j = 0; j < 32; j++) asm volatile("" : "+v"(w1f[j]));

    // ---- phase 1: gather E-rows, build X-frags into As, xsum ----
    // wave w handles tile w, and tile w+4 when w < 3. rows >= 100 clamp to row-64.
    #pragma unroll 1
    for (int ti = 0; ti < 2; ti++) {
        const int tile = wave + ti * 4;
        if (tile >= NT) break;
        const int row = tile * 16 + col;
        const int rc  = (row < HH) ? row : row - 64;
        const int ih  = hidx[rc];
        const int ir  = hreg[rc];
        const float* ph = E_hist + (size_t)ih * DD + quad * 8;
        const float* pr = E_reg  + (size_t)ir * DD + quad * 8;
        unsigned short* ap = &As[tile * 4096];
        float4 g[16];
        #pragma unroll
        for (int s = 0; s < 4; s++) {
            g[2*s]     = *(const float4*)(ph + s * 32);
            g[2*s + 1] = *(const float4*)(ph + s * 32 + 4);
            g[8 + 2*s] = *(const float4*)(pr + s * 32);
            g[9 + 2*s] = *(const float4*)(pr + s * 32 + 4);
        }
        float acc = 0.f;
        #pragma unroll
        for (int s = 0; s < 8; s++) CONSUME(g[2*s], g[2*s+1], s, ap, tgts, acc);
        float v = acc;
        v += __shfl_xor(v, 16);
        v += __shfl_xor(v, 32);
        if (quad == 0) xsum[row] = v;      // rows >= HH written, never read
    }

    // per-strip bias/w2 constants: 32 regs
    f32x4 bbv[4], wwv[4];
    #pragma unroll
    for (int st = 0; st < 4; st++) {
        bbv[st] = *(const f32x4*)&b1s[(wave * 4 + st) * 16 + quad * 4];
        wwv[st] = *(const f32x4*)&w2s[(wave * 4 + st) * 16 + quad * 4];
    }

    __syncthreads();   // P2 — As complete

    // ---- phase 2: sweep 7 m-tiles x this wave's 4 n-strips ----
    #pragma unroll 1
    for (int i = 0; i < NT; i++) {
        int mt = wave * 2 + i; if (mt >= NT) mt -= NT;   // stagger start
        const unsigned short* ap = &As[mt * 4096];
        f32x4 c0 = {0,0,0,0}, c1 = {0,0,0,0}, c2 = {0,0,0,0}, c3 = {0,0,0,0};
        #pragma unroll
        for (int s = 0; s < 8; s++) {
            bf16x8 xf = *(const bf16x8*)(ap + (size_t)(s * 64 + lane) * 8);
            c0 = __builtin_amdgcn_mfma_f32_16x16x32_bf16(w1f[s],      xf, c0, 0, 0, 0);
            c1 = __builtin_amdgcn_mfma_f32_16x16x32_bf16(w1f[8 + s],  xf, c1, 0, 0, 0);
            c2 = __builtin_amdgcn_mfma_f32_16x16x32_bf16(w1f[16 + s], xf, c2, 0, 0, 0);
            c3 = __builtin_amdgcn_mfma_f32_16x16x32_bf16(w1f[24 + s], xf, c3, 0, 0, 0);
        }
        float sp = 0.f;
        #pragma unroll
        for (int r = 0; r < 4; r++) {
            float z0 = c0[r] + bbv[0][r];
            float z1 = c1[r] + bbv[1][r];
            float z2 = c2[r] + bbv[2][r];
            float z3 = c3[r] + bbv[3][r];
            sp += ((z0 > 0.f) ? z0 * wwv[0][r] : 0.f) + ((z1 > 0.f) ? z1 * wwv[1][r] : 0.f)
                + ((z2 > 0.f) ? z2 * wwv[2][r] : 0.f) + ((z3 > 0.f) ? z3 * wwv[3][r] : 0.f);
        }
        sp += __shfl_xor(sp, 16);
        sp += __shfl_xor(sp, 32);
        if (quad == 0) scorep[wave][mt * 16 + col] = sp;
    }
    __syncthreads();   // P3

    // ---- phase 3: cross-wave score reduce, masked exp, denom^BETA, sigmoid ----
    float sc = 0.f;
    if (t < 112) {
        #pragma unroll
        for (int w = 0; w < 4; w++) sc += scorep[w][t];
    }
    const float dist = tdist * s_sumE;
    if (t < HH) {
        float e = (hidx[t] != tg) ? expf(sc + dist) : 0.f;
        eA[t]  = e;
        exs[t] = e * xsum[t];
    }
    __syncthreads();
    if (t < 64) {
        float s1 = eA[t]  + ((t + 64 < HH) ? eA[t + 64]  : 0.f);
        float s2 = exs[t] + ((t + 64 < HH) ? exs[t + 64] : 0.f);
        #pragma unroll
        for (int off = 32; off; off >>= 1) {
            s1 += __shfl_xor(s1, off);
            s2 += __shfl_xor(s2, off);
        }
        if (t == 0) {
            float pred = s2 / sqrtf(s1);   // exp_sum^0.5 (BETA=0.5)
            out[b] = 1.f / (1.f + expf(-pred));
        }
    }
}

extern "C" void kernel_launch(void* const* d_in, const int* in_sizes, int n_in,
                              void* d_out, int out_size, void* d_ws, size_t ws_size,
                              hipStream_t stream) {
    const int*   history         = (const int*)d_in[0];
    const int*   target          = (const int*)d_in[1];
    const int*   history_region  = (const int*)d_in[2];
    const int*   target_region   = (const int*)d_in[3];
    const float* target_distance = (const float*)d_in[4];
    const float* E_hist          = (const float*)d_in[5];
    const float* E_tgt           = (const float*)d_in[6];
    const float* E_reg           = (const float*)d_in[7];
    const float* E_dist          = (const float*)d_in[8];
    const float* W1              = (const float*)d_in[9];
    const float* b1              = (const float*)d_in[10];
    const float* w2              = (const float*)d_in[11];

    unsigned short* W1p = (unsigned short*)d_ws;  // 131072 B
    const int B = in_sizes[1];

    w1_pack<<<32, 256, 0, stream>>>(W1, W1p);
    nais_kernel<<<B, 256, 0, stream>>>(history, target, history_region, target_region,
                                       target_distance, E_hist, E_tgt, E_reg, E_dist,
                                       b1, w2, W1p, (float*)d_out);
}

// Round 9
// 175.774 us; speedup vs baseline: 1.5459x; 1.0180x over previous
//
#include <hip/hip_runtime.h>
#include <stdint.h>

typedef __attribute__((ext_vector_type(8))) short bf16x8;
typedef __attribute__((ext_vector_type(4))) float f32x4;

#define HH  100   // history length
#define DD  128   // embedding dim d
#define HID 256   // hidden width / concat dim
#define NT  7     // m-tiles (112 rows >= 100)
#define NE  4     // elements per block (amortizes the 128 KB W1p refetch)

__device__ __forceinline__ unsigned short f2bf(float f) {
    unsigned int u = __float_as_uint(f);
    u += 0x7fffu + ((u >> 16) & 1u);   // RNE
    return (unsigned short)(u >> 16);
}

// Pack W1 (256x256 f32, [n][k]) into MFMA fragment order, bf16 (runs once).
// unit = (st*8+s)*64 + lane holds W1[st*16 + (lane&15)][s*32 + (lane>>4)*8 + j]
__global__ void w1_pack(const float* __restrict__ W1, unsigned short* __restrict__ W1p) {
    int unit = blockIdx.x * 256 + threadIdx.x;   // 0..8191
    int lane = unit & 63;
    int s    = (unit >> 6) & 7;
    int st   = unit >> 9;
    int col  = lane & 15, quad = lane >> 4;
    const float* src = W1 + (size_t)(st * 16 + col) * HID + s * 32 + quad * 8;
    union { unsigned short u[8]; bf16x8 v; } o;
    #pragma unroll
    for (int j = 0; j < 8; j++) o.u[j] = f2bf(src[j]);
    *(bf16x8*)(W1p + (size_t)unit * 8) = o.v;
}

// pure-VALU packed bf16 convert (no memory side effects — safe asm)
__device__ __forceinline__ unsigned int cvt_pk_bf16(float lo, float hi) {
    unsigned int r;   // r[15:0]=bf16(lo), r[31:16]=bf16(hi)
    asm("v_cvt_pk_bf16_f32 %0, %1, %2" : "=v"(r) : "v"(lo), "v"(hi));
    return r;
}

// multiply 2 float4 by tgt slice, accumulate xsum, cvt+store one A-frag s-step
#define CONSUME(V0, V1, S, AP, TGT, ACC) do {                                     \
    const float* tp_ = (TGT) + (S) * 32 + quad * 8;                               \
    float4 t0_ = *(const float4*)tp_, t1_ = *(const float4*)(tp_ + 4);            \
    float x0=(V0).x*t0_.x, x1=(V0).y*t0_.y, x2=(V0).z*t0_.z, x3=(V0).w*t0_.w;     \
    float x4=(V1).x*t1_.x, x5=(V1).y*t1_.y, x6=(V1).z*t1_.z, x7=(V1).w*t1_.w;     \
    (ACC) += (x0+x1)+(x2+x3)+((x4+x5)+(x6+x7));                                   \
    union { unsigned int u[4]; int4 v; } fb_;                                     \
    fb_.u[0]=cvt_pk_bf16(x0,x1); fb_.u[1]=cvt_pk_bf16(x2,x3);                     \
    fb_.u[2]=cvt_pk_bf16(x4,x5); fb_.u[3]=cvt_pk_bf16(x6,x7);                     \
    *(int4*)((AP) + (size_t)((S) * 64 + lane) * 8) = fb_.v;                       \
} while (0)

// r8 structure (4-wave blocks, wave owns 64 n-cols, W1 frags in 128 pinned regs,
// 2 blocks/CU) + NE-element loop per block. W1p is loaded from L2 ONCE per block
// instead of once per element: per-element VMEM traffic drops 244 -> ~148 KB,
// testing the theory that the per-CU L2-return path is the invariant ~64 µs floor.
// grid = B/NE = 512 -> every block resident from t=0 (no dispatch rounds).
__global__ __launch_bounds__(256, 2) void nais_kernel(
    const int* __restrict__ history,           // [B,HH]
    const int* __restrict__ target,            // [B]
    const int* __restrict__ history_region,    // [B,HH]
    const int* __restrict__ target_region,     // [B]
    const float* __restrict__ target_distance, // [B]
    const float* __restrict__ E_hist,          // [item,128]
    const float* __restrict__ E_tgt,           // [item,128]
    const float* __restrict__ E_reg,           // [region,128]
    const float* __restrict__ E_dist,          // [16,128]
    const float* __restrict__ b1,              // [256]
    const float* __restrict__ w2,              // [256]
    const unsigned short* __restrict__ W1p,    // packed bf16 fragments (128 KB)
    float* __restrict__ out,                   // [B]
    int Btot)
{
    __shared__ __align__(16) unsigned short As[NT * 4096];   // 56 KB
    __shared__ __align__(16) float tgts[HID];
    __shared__ __align__(16) float b1s[HID];
    __shared__ __align__(16) float w2s[HID];
    __shared__ __align__(16) float scorep[4][112];
    __shared__ __align__(16) float xsum[112];
    __shared__ float eA[HH];
    __shared__ float exs[HH];
    __shared__ int hidx[HH];
    __shared__ int hreg[HH];
    __shared__ float s_sumE;

    const int t    = threadIdx.x;                // 0..255
    const int lane = t & 63;
    const int wave = t >> 6;                     // 0..3
    const int col  = lane & 15;
    const int quad = lane >> 4;

    const int base = blockIdx.x * NE;

    // ---- block prologue: b1/w2, sum(E_dist[0]) ----
    if (wave == 3) {
        *(float4*)(b1s + lane * 4) = *(const float4*)(b1 + lane * 4);
        *(float4*)(w2s + lane * 4) = *(const float4*)(w2 + lane * 4);
    }
    if (wave == 1) {
        float v = E_dist[lane] + E_dist[64 + lane];
        #pragma unroll
        for (int off = 32; off; off >>= 1) v += __shfl_xor(v, off);
        if (lane == 0) s_sumE = v;
    }

    // ---- W1 fragments -> 128 registers/wave (4 strips x 8 s), pinned once ----
    bf16x8 w1f[32];
    #pragma unroll
    for (int j = 0; j < 32; j++) {
        const int unit = ((wave * 4 + (j >> 3)) * 8 + (j & 7)) * 64 + lane;
        w1f[j] = *(const bf16x8*)(W1p + (size_t)unit * 8);
    }
    #pragma unroll
    for (int j = 0; j < 32; j++) asm volatile("" : "+v"(w1f[j]));

    __syncthreads();   // b1s/w2s ready

    // per-strip bias/w2 constants: 32 regs, hoisted out of the element loop
    f32x4 bbv[4], wwv[4];
    #pragma unroll
    for (int st = 0; st < 4; st++) {
        bbv[st] = *(const f32x4*)&b1s[(wave * 4 + st) * 16 + quad * 4];
        wwv[st] = *(const f32x4*)&w2s[(wave * 4 + st) * 16 + quad * 4];
    }

    #pragma unroll 1
    for (int e = 0; e < NE; e++) {
        const int b = base + e;
        if (b >= Btot) break;

        const int   tg    = target[b];
        const float tdist = target_distance[b];

        // ---- phase 0: stage indices + tgt vector ----
        if (t < HH) {
            hidx[t] = history[b * HH + t];
            hreg[t] = history_region[b * HH + t];
        }
        if (wave == 2) {
            float4 v;
            if (lane < 32) v = *(const float4*)(E_tgt + (size_t)tg * DD + lane * 4);
            else           v = *(const float4*)(E_reg + (size_t)target_region[b] * DD + (lane - 32) * 4);
            *(float4*)(tgts + lane * 4) = v;
        }
        __syncthreads();   // B0

        // ---- phase 1: gather E-rows, build X-frags into As, xsum ----
        // wave w handles tile w, and tile w+4 when w < 3. rows >= 100 clamp to row-64.
        #pragma unroll 1
        for (int ti = 0; ti < 2; ti++) {
            const int tile = wave + ti * 4;
            if (tile >= NT) break;
            const int row = tile * 16 + col;
            const int rc  = (row < HH) ? row : row - 64;
            const int ih  = hidx[rc];
            const int ir  = hreg[rc];
            const float* ph = E_hist + (size_t)ih * DD + quad * 8;
            const float* pr = E_reg  + (size_t)ir * DD + quad * 8;
            unsigned short* ap = &As[tile * 4096];
            float4 g[16];
            #pragma unroll
            for (int s = 0; s < 4; s++) {
                g[2*s]     = *(const float4*)(ph + s * 32);
                g[2*s + 1] = *(const float4*)(ph + s * 32 + 4);
                g[8 + 2*s] = *(const float4*)(pr + s * 32);
                g[9 + 2*s] = *(const float4*)(pr + s * 32 + 4);
            }
            float acc = 0.f;
            #pragma unroll
            for (int s = 0; s < 8; s++) CONSUME(g[2*s], g[2*s+1], s, ap, tgts, acc);
            float v = acc;
            v += __shfl_xor(v, 16);
            v += __shfl_xor(v, 32);
            if (quad == 0) xsum[row] = v;      // rows >= HH written, never read
        }
        __syncthreads();   // B1 — As complete

        // ---- phase 2: sweep 7 m-tiles x this wave's 4 n-strips ----
        #pragma unroll 1
        for (int i = 0; i < NT; i++) {
            int mt = wave * 2 + i; if (mt >= NT) mt -= NT;   // stagger start
            const unsigned short* ap = &As[mt * 4096];
            f32x4 c0 = {0,0,0,0}, c1 = {0,0,0,0}, c2 = {0,0,0,0}, c3 = {0,0,0,0};
            #pragma unroll
            for (int s = 0; s < 8; s++) {
                bf16x8 xf = *(const bf16x8*)(ap + (size_t)(s * 64 + lane) * 8);
                c0 = __builtin_amdgcn_mfma_f32_16x16x32_bf16(w1f[s],      xf, c0, 0, 0, 0);
                c1 = __builtin_amdgcn_mfma_f32_16x16x32_bf16(w1f[8 + s],  xf, c1, 0, 0, 0);
                c2 = __builtin_amdgcn_mfma_f32_16x16x32_bf16(w1f[16 + s], xf, c2, 0, 0, 0);
                c3 = __builtin_amdgcn_mfma_f32_16x16x32_bf16(w1f[24 + s], xf, c3, 0, 0, 0);
            }
            float sp = 0.f;
            #pragma unroll
            for (int r = 0; r < 4; r++) {
                float z0 = c0[r] + bbv[0][r];
                float z1 = c1[r] + bbv[1][r];
                float z2 = c2[r] + bbv[2][r];
                float z3 = c3[r] + bbv[3][r];
                sp += ((z0 > 0.f) ? z0 * wwv[0][r] : 0.f) + ((z1 > 0.f) ? z1 * wwv[1][r] : 0.f)
                    + ((z2 > 0.f) ? z2 * wwv[2][r] : 0.f) + ((z3 > 0.f) ? z3 * wwv[3][r] : 0.f);
            }
            sp += __shfl_xor(sp, 16);
            sp += __shfl_xor(sp, 32);
            if (quad == 0) scorep[wave][mt * 16 + col] = sp;
        }
        __syncthreads();   // B2

        // ---- phase 3: cross-wave score reduce, masked exp, denom^BETA, sigmoid ----
        float sc = 0.f;
        if (t < 112) {
            #pragma unroll
            for (int w = 0; w < 4; w++) sc += scorep[w][t];
        }
        const float dist = tdist * s_sumE;
        if (t < HH) {
            float ev = (hidx[t] != tg) ? expf(sc + dist) : 0.f;
            eA[t]  = ev;
            exs[t] = ev * xsum[t];
        }
        __syncthreads();   // B3
        if (t < 64) {
            float s1 = eA[t]  + ((t + 64 < HH) ? eA[t + 64]  : 0.f);
            float s2 = exs[t] + ((t + 64 < HH) ? exs[t + 64] : 0.f);
            #pragma unroll
            for (int off = 32; off; off >>= 1) {
                s1 += __shfl_xor(s1, off);
                s2 += __shfl_xor(s2, off);
            }
            if (t == 0) {
                float pred = s2 / sqrtf(s1);   // exp_sum^0.5 (BETA=0.5)
                out[b] = 1.f / (1.f + expf(-pred));
            }
        }
        // no barrier needed here: next iteration's writes (hidx/tgts/As) are
        // separated from this phase's readers by B0/B1 of the next iteration,
        // and eA/exs are rewritten only after B0,B1,B2 of iteration e+1.
    }
}

extern "C" void kernel_launch(void* const* d_in, const int* in_sizes, int n_in,
                              void* d_out, int out_size, void* d_ws, size_t ws_size,
                              hipStream_t stream) {
    const int*   history         = (const int*)d_in[0];
    const int*   target          = (const int*)d_in[1];
    const int*   history_region  = (const int*)d_in[2];
    const int*   target_region   = (const int*)d_in[3];
    const float* target_distance = (const float*)d_in[4];
    const float* E_hist          = (const float*)d_in[5];
    const float* E_tgt           = (const float*)d_in[6];
    const float* E_reg           = (const float*)d_in[7];
    const float* E_dist          = (const float*)d_in[8];
    const float* W1              = (const float*)d_in[9];
    const float* b1              = (const float*)d_in[10];
    const float* w2              = (const float*)d_in[11];

    unsigned short* W1p = (unsigned short*)d_ws;  // 131072 B
    const int B = in_sizes[1];

    const int grid = (B + NE - 1) / NE;           // 2048/4 = 512 = 2 blocks/CU

    w1_pack<<<32, 256, 0, stream>>>(W1, W1p);
    nais_kernel<<<grid, 256, 0, stream>>>(history, target, history_region, target_region,
                                          target_distance, E_hist, E_tgt, E_reg, E_dist,
                                          b1, w2, W1p, (float*)d_out, B);
}